// Round 3
// baseline (373.317 us; speedup 1.0000x reference)
//
#include <hip/hip_runtime.h>
#include <hip/hip_bf16.h>

// Problem constants (fixed by setup_inputs)
#define T_SZ 32
#define B_SZ 512
#define F_SZ 2048
#define H_SZ 2048
#define M_SZ (T_SZ * B_SZ)   // 16384 GEMM rows

// GEMM tile: BM=256, BN=128, BK=64. 4 waves (2M x 2N), wave tile 128x64 = 4x2 MFMA frags
// (acc = 128 regs -> register file caps at 2 waves/SIMD; TLP comes from 2 INDEPENDENT
// blocks/CU: 48 KB LDS/block, 2x4 waves = 2/SIMD, 2x~240 regs = the full 512-reg file).
// 2-phase/kt schedule, counted vmcnt(2), no sched_barrier pins inside phases.
#define BM 256
#define BN 128
#define BK 64
#define NT (F_SZ / BK)            // 32 K-tiles
#define ABYTES (BM * BK)          // 16 KB
#define BBYTES (BN * BK)          // 8 KB
#define TILE_BYTES (ABYTES + BBYTES)  // 24 KB per buffer

typedef int   i32x8  __attribute__((ext_vector_type(8)));    // 32 fp8 = 8 VGPRs (MFMA A/B frag)
typedef float f32x16 __attribute__((ext_vector_type(16)));   // 32x32 MFMA C/D frag

__device__ __forceinline__ void gload_lds16(const void* g, void* l) {
    // async global->LDS, 16 B/lane (global_load_lds_dwordx4).
    // LDS dest is wave-uniform base + lane*16; the bank swizzle is implemented by
    // permuting the per-lane GLOBAL source address (LDS side stays linear).
    __builtin_amdgcn_global_load_lds(
        (const __attribute__((address_space(1))) unsigned int*)g,
        (__attribute__((address_space(3))) unsigned int*)l,
        16, 0, 0);
}

__device__ __forceinline__ float bf16_bits_to_f32(unsigned short u) {
    return __uint_as_float(((unsigned)u) << 16);
}

__device__ __forceinline__ void sbar() {
    __builtin_amdgcn_sched_barrier(0);
    __builtin_amdgcn_s_barrier();
    __builtin_amdgcn_sched_barrier(0);
}

#define MFMA_FP8(a, b, c) __builtin_amdgcn_mfma_scale_f32_32x32x64_f8f6f4( \
        (a), (b), (c), 0 /*A e4m3*/, 0 /*B e4m3*/, 0, 0x7f7f7f7f, 0, 0x7f7f7f7f)

// ---------------- fp32 -> fp8 e4m3 (OCP), 8 elems/thread, optional pre-scale ----------------
__global__ __launch_bounds__(256) void cvt_fp8_kernel(const float* __restrict__ in,
                                                      unsigned int* __restrict__ out,
                                                      float scale, int n8) {
    int i = blockIdx.x * 256 + threadIdx.x;
    if (i >= n8) return;
    float4 v0 = ((const float4*)in)[2 * i];
    float4 v1 = ((const float4*)in)[2 * i + 1];
    int w0 = __builtin_amdgcn_cvt_pk_fp8_f32(v0.x * scale, v0.y * scale, 0, false);
    w0     = __builtin_amdgcn_cvt_pk_fp8_f32(v0.z * scale, v0.w * scale, w0, true);
    int w1 = __builtin_amdgcn_cvt_pk_fp8_f32(v1.x * scale, v1.y * scale, 0, false);
    w1     = __builtin_amdgcn_cvt_pk_fp8_f32(v1.z * scale, v1.w * scale, w1, true);
    ((uint2*)out)[i] = make_uint2((unsigned)w0, (unsigned)w1);
}

// ---------------- zero the row sum-of-squares accumulator (ws is poisoned 0xAA) ----------------
__global__ __launch_bounds__(256) void init_ss_kernel(float4* __restrict__ ss4) {
    ss4[blockIdx.x * 256 + threadIdx.x] = make_float4(0.f, 0.f, 0.f, 0.f);
}

// ---------------- GEMM (MX-fp8) + fused row-SS ----------------
// C[m,n] = (1/256) * sum_k A8[m,k]*B8[n,k] + bias[n];  ss[m] += sum_n C[m,n]^2 (atomic)
//
// Per K-tile kt (2 phases):
//   P0: ds_read bq(cur)[4 b128] + af01(cur)[4]; stage A(kt+1)->buf^1 [4 gloads];
//       setprio(1); 4 MFMA (mi0,mi1 x ni); setprio(0); s_barrier
//   P1: ds_read af23(cur)[4]; stage B(kt+2)->cur.B [2 gloads];
//       setprio(1); 4 MFMA (mi2,mi3 x ni); setprio(0); vmcnt(2); s_barrier
//
// Slot-reuse safety (every restage >= 1 barrier after ALL waves' consuming lgkm-wait):
//   A(kt+1)->buf^1.A : buf^1.A last read kt-1 (af01 consumed P0[kt-1], af23 consumed
//                      P1[kt-1], both before end-P1[kt-1] barrier < P0[kt] stage)  OK
//   B(kt+2)->cur.B   : bq(cur) lgkm-consumed by P0[kt]'s MFMA < end-P0 barrier < P1 stage  OK
// vmcnt FIFO induction (A=4 loads, B=2): entry queue [B(kt+1):2]; +A(kt+1):4; +B(kt+2):2;
//   vmcnt(2) drains exactly tile kt+1, keeps B(kt+2) in flight across the barrier.
__global__ __launch_bounds__(256, 2) void gemm_fp8_kernel(const unsigned char* __restrict__ A,   // [M_SZ,F_SZ] fp8
                                                          const unsigned char* __restrict__ Bt,  // [H_SZ,F_SZ] fp8 (x256)
                                                          const float* __restrict__ bias,        // [H_SZ]
                                                          __hip_bfloat16* __restrict__ C,        // [M_SZ,H_SZ] bf16
                                                          float* __restrict__ ss)                // [M_SZ] atomic SS
{
    __shared__ __align__(16) unsigned char smem[2 * TILE_BYTES];  // 48 KB -> 2 blocks/CU

    const int tid  = threadIdx.x;
    const int lane = tid & 63;
    const int wave = tid >> 6;           // 0..3
    const int wm   = wave >> 1;          // 0..1 -> 128-row half
    const int wn   = wave & 1;           // 0..1 -> 64-col half
    const int l31  = lane & 31;
    const int kh   = lane >> 5;          // k-half within the 64B MFMA slice

    // bijective XCD-chunk swizzle: 1024 blocks, XCD k (= flat%8) gets logical ids
    // [k*128, (k+1)*128) -> 8 m-blocks x all 16 n-blocks; per-kt working set per XCD
    // = 128KB A-slice + 128KB B-slice -> L2-resident.
    const int flat = blockIdx.y * 16 + blockIdx.x;
    const int swz  = (flat & 7) * 128 + (flat >> 3);
    const int n0   = (swz & 15) * BN;
    const int m0   = (swz >> 4) * BM;

    const unsigned char* const Ap = A  + (size_t)m0 * F_SZ;
    const unsigned char* const Bp = Bt + (size_t)n0 * F_SZ;

    // --- precomputed per-thread staging offsets (row-major 64B rows, 4 x 16B units,
    //     XOR swizzle phys_u = log_u ^ (row&3), applied on the global source) ---
    int sAg[4], sAl[4];                  // A: 1024 chunks, 4/thread
    #pragma unroll
    for (int j = 0; j < 4; ++j) {
        const int c = j * 256 + tid;
        const int row = c >> 2;
        const int u = (c & 3) ^ (row & 3);
        sAg[j] = row * F_SZ + u * 16;
        sAl[j] = c * 16;
    }
    int sBg[2], sBl[2];                  // B: 512 chunks, 2/thread
    #pragma unroll
    for (int j = 0; j < 2; ++j) {
        const int c = j * 256 + tid;
        const int row = c >> 2;
        const int u = (c & 3) ^ (row & 3);
        sBg[j] = row * F_SZ + u * 16;
        sBl[j] = c * 16;
    }

    // --- precomputed per-lane fragment read offsets ---
    int aoff[4][2], boff[2][2];
    #pragma unroll
    for (int mi = 0; mi < 4; ++mi) {
        const int ra = wm * 128 + mi * 32 + l31;
        #pragma unroll
        for (int j = 0; j < 2; ++j)
            aoff[mi][j] = ra * BK + (((kh * 2 + j) ^ (ra & 3)) * 16);
    }
    #pragma unroll
    for (int ni = 0; ni < 2; ++ni) {
        const int rb = wn * 64 + ni * 32 + l31;
        #pragma unroll
        for (int j = 0; j < 2; ++j)
            boff[ni][j] = rb * BK + (((kh * 2 + j) ^ (rb & 3)) * 16);
    }

    auto stageA = [&](int p, int kt) {
        unsigned char* const d = smem + p * TILE_BYTES;
        #pragma unroll
        for (int j = 0; j < 4; ++j) gload_lds16(Ap + kt * BK + sAg[j], d + sAl[j]);
    };
    auto stageB = [&](int p, int kt) {
        unsigned char* const d = smem + p * TILE_BYTES + ABYTES;
        #pragma unroll
        for (int j = 0; j < 2; ++j) gload_lds16(Bp + kt * BK + sBg[j], d + sBl[j]);
    };

    f32x16 acc[4][2] = {};

    // prologue: B0,A0 -> buf0; B1 -> buf1.  Queue [B0:2,A0:4,B1:2] -> vmcnt(2) = tile0 landed.
    stageB(0, 0);
    stageA(0, 0);
    stageB(1, 1);
    asm volatile("s_waitcnt vmcnt(2)" ::: "memory");
    sbar();

    #pragma unroll 1
    for (int kt = 0; kt < NT; ++kt) {
        unsigned char* const buf = smem + (kt & 1) * TILE_BYTES;
        unsigned char* const Bs  = buf + ABYTES;

        i32x8 a01[2], a23[2], bq[2];

        // ---- P0 ----
        #pragma unroll
        for (int ni = 0; ni < 2; ++ni) {
            ((int4*)&bq[ni])[0] = *(const int4*)(Bs + boff[ni][0]);
            ((int4*)&bq[ni])[1] = *(const int4*)(Bs + boff[ni][1]);
        }
        #pragma unroll
        for (int mi = 0; mi < 2; ++mi) {
            ((int4*)&a01[mi])[0] = *(const int4*)(buf + aoff[mi][0]);
            ((int4*)&a01[mi])[1] = *(const int4*)(buf + aoff[mi][1]);
        }
        if (kt + 1 < NT) stageA((kt + 1) & 1, kt + 1);

        __builtin_amdgcn_s_setprio(1);
        acc[0][0] = MFMA_FP8(a01[0], bq[0], acc[0][0]);
        acc[0][1] = MFMA_FP8(a01[0], bq[1], acc[0][1]);
        acc[1][0] = MFMA_FP8(a01[1], bq[0], acc[1][0]);
        acc[1][1] = MFMA_FP8(a01[1], bq[1], acc[1][1]);
        __builtin_amdgcn_s_setprio(0);
        sbar();

        // ---- P1 ----
        #pragma unroll
        for (int mi = 0; mi < 2; ++mi) {
            ((int4*)&a23[mi])[0] = *(const int4*)(buf + aoff[2 + mi][0]);
            ((int4*)&a23[mi])[1] = *(const int4*)(buf + aoff[2 + mi][1]);
        }
        if (kt + 2 < NT) stageB(kt & 1, kt + 2);

        __builtin_amdgcn_s_setprio(1);
        acc[2][0] = MFMA_FP8(a23[0], bq[0], acc[2][0]);
        acc[2][1] = MFMA_FP8(a23[0], bq[1], acc[2][1]);
        acc[3][0] = MFMA_FP8(a23[1], bq[0], acc[3][0]);
        acc[3][1] = MFMA_FP8(a23[1], bq[1], acc[3][1]);
        __builtin_amdgcn_s_setprio(0);

        if (kt < NT - 2)       { asm volatile("s_waitcnt vmcnt(2)" ::: "memory"); }
        else if (kt == NT - 2) { asm volatile("s_waitcnt vmcnt(0)" ::: "memory"); }
        if (kt < NT - 1) sbar();
    }

    // epilogue: 32x32 C/D layout col=lane&31, row=(r&3)+8*(r>>2)+4*(lane>>5)  (m74/m101-verified)
    float bv[2];
    #pragma unroll
    for (int ni = 0; ni < 2; ++ni) bv[ni] = bias[n0 + wn * 64 + ni * 32 + l31];
    #pragma unroll
    for (int mi = 0; mi < 4; ++mi) {
        const int gmb = m0 + wm * 128 + mi * 32 + 4 * kh;
        #pragma unroll
        for (int r = 0; r < 16; ++r) {
            const int grow = gmb + (r & 3) + 8 * (r >> 2);
            float p = 0.f;
            #pragma unroll
            for (int ni = 0; ni < 2; ++ni) {
                const int gn = n0 + wn * 64 + ni * 32 + l31;
                const float val = acc[mi][ni][r] * (1.0f / 256.0f) + bv[ni];
                C[(size_t)grow * H_SZ + gn] = __float2bfloat16(val);
                p += val * val;
            }
            // cross-lane: sum over the 32 col-lanes (masks<32 stay in-half)
            p += __shfl_xor(p, 1, 64);
            p += __shfl_xor(p, 2, 64);
            p += __shfl_xor(p, 4, 64);
            p += __shfl_xor(p, 8, 64);
            p += __shfl_xor(p, 16, 64);
            if (l31 == 0) atomicAdd(ss + grow, p);
        }
    }
}

// ---------------- LIF scan: 4 columns/thread, inv-norm in LDS, 3-deep load pipeline ----------------
__global__ __launch_bounds__(256) void lif_scan_kernel(const __hip_bfloat16* __restrict__ cur, // [M_SZ,H_SZ]
                                                       const float* __restrict__ ss,           // [M_SZ] sum-of-squares
                                                       float* __restrict__ spk,                // [T,B,H]
                                                       float* __restrict__ cnt)                // [B,H]
{
    __shared__ float s_inv[T_SZ];
    const int gid = blockIdx.x * 256 + threadIdx.x;     // 262144 threads
    const int b   = gid >> 9;                           // uniform within a block
    const int h0  = (gid & 511) * 4;

    if (threadIdx.x < T_SZ)
        s_inv[threadIdx.x] = 1.0f / fmaxf(sqrtf(ss[threadIdx.x * B_SZ + b]), 1e-12f);
    __syncthreads();

    const size_t stride = (size_t)B_SZ * H_SZ;
    const size_t base   = (size_t)b * H_SZ + h0;
    const __hip_bfloat16* p = cur + base;

    ushort4 pk[3];
    pk[0] = *(const ushort4*)(p);
    pk[1] = *(const ushort4*)(p + stride);
    pk[2] = *(const ushort4*)(p + 2 * stride);

    float v[4]  = {0, 0, 0, 0};
    float cn[4] = {0, 0, 0, 0};
    #pragma unroll
    for (int t = 0; t < T_SZ; ++t) {
        const ushort4 k = pk[t % 3];
        if (t + 3 < T_SZ) pk[t % 3] = *(const ushort4*)(p + (size_t)(t + 3) * stride);
        const float inv = s_inv[t];
        float so[4];
        {
            float c;
            c = bf16_bits_to_f32(k.x) * inv; v[0] += (c - v[0]) * 0.5f;
            c = bf16_bits_to_f32(k.y) * inv; v[1] += (c - v[1]) * 0.5f;
            c = bf16_bits_to_f32(k.z) * inv; v[2] += (c - v[2]) * 0.5f;
            c = bf16_bits_to_f32(k.w) * inv; v[3] += (c - v[3]) * 0.5f;
        }
        #pragma unroll
        for (int j = 0; j < 4; ++j) {
            float s = (v[j] >= 1.0f) ? 1.0f : 0.0f;
            so[j] = s;
            cn[j] += s;
            v[j] = (s != 0.f) ? 0.f : v[j];
        }
        *(float4*)(spk + base + (size_t)t * stride) = make_float4(so[0], so[1], so[2], so[3]);
    }
    *(float4*)(cnt + base) = make_float4(cn[0], cn[1], cn[2], cn[3]);
}

extern "C" void kernel_launch(void* const* d_in, const int* in_sizes, int n_in,
                              void* d_out, int out_size, void* d_ws, size_t ws_size,
                              hipStream_t stream) {
    const float* x    = (const float*)d_in[0];   // [T,B,F] fp32
    const float* W    = (const float*)d_in[1];   // [H,F]  fp32
    const float* bias = (const float*)d_in[2];   // [H]    fp32

    float* spk = (float*)d_out;                          // [T,B,H]
    float* cnt = spk + (size_t)T_SZ * B_SZ * H_SZ;       // [B,H]

    char* ws = (char*)d_ws;
    unsigned char* x8    = (unsigned char*)ws;                                   // 33.5 MB
    unsigned char* W8    = x8 + (size_t)M_SZ * F_SZ;                             // 4.2 MB
    __hip_bfloat16* curb = (__hip_bfloat16*)(W8 + (size_t)H_SZ * F_SZ);          // 67.1 MB
    float* ss            = (float*)((char*)curb + (size_t)M_SZ * H_SZ * 2);      // 64 KB

    init_ss_kernel<<<M_SZ / 1024, 256, 0, stream>>>((float4*)ss);
    cvt_fp8_kernel<<<(M_SZ * F_SZ / 8) / 256, 256, 0, stream>>>(x, (unsigned int*)x8, 1.0f,   M_SZ * F_SZ / 8);
    cvt_fp8_kernel<<<(H_SZ * F_SZ / 8) / 256, 256, 0, stream>>>(W, (unsigned int*)W8, 256.0f, H_SZ * F_SZ / 8);
    gemm_fp8_kernel<<<dim3(H_SZ / BN, M_SZ / BM), 256, 0, stream>>>(x8, W8, bias, curb, ss);
    lif_scan_kernel<<<(B_SZ * H_SZ / 4) / 256, 256, 0, stream>>>(curb, ss, spk, cnt);
}

// Round 4
// 363.972 us; speedup vs baseline: 1.0257x; 1.0257x over previous
//
#include <hip/hip_runtime.h>
#include <hip/hip_bf16.h>

// Problem constants (fixed by setup_inputs)
#define T_SZ 32
#define B_SZ 512
#define F_SZ 2048
#define H_SZ 2048
#define M_SZ (T_SZ * B_SZ)   // 16384 GEMM rows

// GEMM tile: BM=256, BN=128, BK=64. 4 waves (2M x 2N), wave tile 128x64 = 4x2 MFMA frags
// (acc = 128 regs caps at 2 waves/SIMD; TLP from 2 INDEPENDENT blocks/CU).
// TRIPLE-buffered LDS (72 KB/block, 2 blocks = 144 KB <= 160): tile kt+2 staged during
// kt -> ~2 kt (~4000 cy) of load flight vs ~900 cy HBM latency. ONE barrier per kt.
// Swizzle fixed for 64B rows: phys_u = log_u ^ ((row>>1)&3)  (R3's (row&3) only covered
// 4 of 8 bank-quads -> 18.9M conflicts; this covers all 8 across any 8 rows).
#define BM 256
#define BN 128
#define BK 64
#define NT (F_SZ / BK)            // 32 K-tiles
#define ABYTES (BM * BK)          // 16 KB
#define BBYTES (BN * BK)          // 8 KB
#define TILE_BYTES (ABYTES + BBYTES)  // 24 KB per buffer

typedef int   i32x8  __attribute__((ext_vector_type(8)));    // 32 fp8 = 8 VGPRs (MFMA A/B frag)
typedef float f32x16 __attribute__((ext_vector_type(16)));   // 32x32 MFMA C/D frag

__device__ __forceinline__ void gload_lds16(const void* g, void* l) {
    // async global->LDS, 16 B/lane (global_load_lds_dwordx4).
    // LDS dest is wave-uniform base + lane*16; the bank swizzle is implemented by
    // permuting the per-lane GLOBAL source address (LDS side stays linear).
    __builtin_amdgcn_global_load_lds(
        (const __attribute__((address_space(1))) unsigned int*)g,
        (__attribute__((address_space(3))) unsigned int*)l,
        16, 0, 0);
}

__device__ __forceinline__ float bf16_bits_to_f32(unsigned short u) {
    return __uint_as_float(((unsigned)u) << 16);
}

__device__ __forceinline__ void sbar() {
    __builtin_amdgcn_sched_barrier(0);
    __builtin_amdgcn_s_barrier();
    __builtin_amdgcn_sched_barrier(0);
}

#define MFMA_FP8(a, b, c) __builtin_amdgcn_mfma_scale_f32_32x32x64_f8f6f4( \
        (a), (b), (c), 0 /*A e4m3*/, 0 /*B e4m3*/, 0, 0x7f7f7f7f, 0, 0x7f7f7f7f)

// ---------------- fp32 -> fp8 e4m3 (OCP), 8 elems/thread, optional pre-scale ----------------
__global__ __launch_bounds__(256) void cvt_fp8_kernel(const float* __restrict__ in,
                                                      unsigned int* __restrict__ out,
                                                      float scale, int n8) {
    int i = blockIdx.x * 256 + threadIdx.x;
    if (i >= n8) return;
    float4 v0 = ((const float4*)in)[2 * i];
    float4 v1 = ((const float4*)in)[2 * i + 1];
    int w0 = __builtin_amdgcn_cvt_pk_fp8_f32(v0.x * scale, v0.y * scale, 0, false);
    w0     = __builtin_amdgcn_cvt_pk_fp8_f32(v0.z * scale, v0.w * scale, w0, true);
    int w1 = __builtin_amdgcn_cvt_pk_fp8_f32(v1.x * scale, v1.y * scale, 0, false);
    w1     = __builtin_amdgcn_cvt_pk_fp8_f32(v1.z * scale, v1.w * scale, w1, true);
    ((uint2*)out)[i] = make_uint2((unsigned)w0, (unsigned)w1);
}

// ---------------- zero the row sum-of-squares accumulator (ws is poisoned 0xAA) ----------------
__global__ __launch_bounds__(256) void init_ss_kernel(float4* __restrict__ ss4) {
    ss4[blockIdx.x * 256 + threadIdx.x] = make_float4(0.f, 0.f, 0.f, 0.f);
}

// ---------------- GEMM (MX-fp8) + fused row-SS ----------------
// C[m,n] = (1/256) * sum_k A8[m,k]*B8[n,k] + bias[n];  ss[m] += sum_n C[m,n]^2 (atomic)
//
// Per K-tile kt (single phase, one barrier):
//   ds_read bq(4 b128) + a01(4) + a23(4) from buf[kt%3];
//   stage A(kt+2)(4 gloads) + B(kt+2)(2) into buf[(kt+2)%3];
//   setprio(1); 8 MFMA; setprio(0);
//   vmcnt(6)  [drains exactly tile kt+1; kt+2's 6 loads stay in flight]; s_barrier
//
// Slot-reuse safety: buf[(kt+2)%3] was last ds_read at kt-1; those reads are consumed
// by kt-1's MFMAs (compiler lgkm waits) BEFORE the end-of-(kt-1) barrier, which every
// wave passes before any wave stages at kt.  Cross-wave DMA visibility: each wave's
// vmcnt(6) at end of kt+1 drains its own T(kt+2) chunks; the following barrier makes
// them visible to all waves before kt+2's reads.
// vmcnt FIFO induction (A:4+B:2 per tile): after kt's stages the queue is
// [T(kt+1):6, T(kt+2):6] -> vmcnt(6) == T(kt+1) landed.
__global__ __launch_bounds__(256, 2) void gemm_fp8_kernel(const unsigned char* __restrict__ A,   // [M_SZ,F_SZ] fp8
                                                          const unsigned char* __restrict__ Bt,  // [H_SZ,F_SZ] fp8 (x256)
                                                          const float* __restrict__ bias,        // [H_SZ]
                                                          __hip_bfloat16* __restrict__ C,        // [M_SZ,H_SZ] bf16
                                                          float* __restrict__ ss)                // [M_SZ] atomic SS
{
    __shared__ __align__(16) unsigned char smem[3 * TILE_BYTES];  // 72 KB -> 2 blocks/CU

    const int tid  = threadIdx.x;
    const int lane = tid & 63;
    const int wave = tid >> 6;           // 0..3
    const int wm   = wave >> 1;          // 0..1 -> 128-row half
    const int wn   = wave & 1;           // 0..1 -> 64-col half
    const int l31  = lane & 31;
    const int kh   = lane >> 5;          // k-half within the 64B MFMA slice

    // bijective XCD-chunk swizzle: 1024 blocks, XCD k (= flat%8) gets logical ids
    // [k*128, (k+1)*128) -> 8 m-blocks x all 16 n-blocks; per-kt working set per XCD
    // = 128KB A-slice + 128KB B-slice -> L2-resident.
    const int flat = blockIdx.y * 16 + blockIdx.x;
    const int swz  = (flat & 7) * 128 + (flat >> 3);
    const int n0   = (swz & 15) * BN;
    const int m0   = (swz >> 4) * BM;

    const unsigned char* const Ap = A  + (size_t)m0 * F_SZ;
    const unsigned char* const Bp = Bt + (size_t)n0 * F_SZ;

    // --- precomputed per-thread staging offsets (row-major 64B rows, 4 x 16B units,
    //     XOR swizzle phys_u = log_u ^ ((row>>1)&3), applied on the global source) ---
    int sAg[4], sAl[4];                  // A: 1024 chunks, 4/thread
    #pragma unroll
    for (int j = 0; j < 4; ++j) {
        const int c = j * 256 + tid;
        const int row = c >> 2;
        const int u = (c & 3) ^ ((row >> 1) & 3);
        sAg[j] = row * F_SZ + u * 16;
        sAl[j] = c * 16;
    }
    int sBg[2], sBl[2];                  // B: 512 chunks, 2/thread
    #pragma unroll
    for (int j = 0; j < 2; ++j) {
        const int c = j * 256 + tid;
        const int row = c >> 2;
        const int u = (c & 3) ^ ((row >> 1) & 3);
        sBg[j] = row * F_SZ + u * 16;
        sBl[j] = c * 16;
    }

    // --- precomputed per-lane fragment read offsets (same involution) ---
    int aoff[4][2], boff[2][2];
    #pragma unroll
    for (int mi = 0; mi < 4; ++mi) {
        const int ra = wm * 128 + mi * 32 + l31;
        #pragma unroll
        for (int j = 0; j < 2; ++j)
            aoff[mi][j] = ra * BK + (((kh * 2 + j) ^ ((ra >> 1) & 3)) * 16);
    }
    #pragma unroll
    for (int ni = 0; ni < 2; ++ni) {
        const int rb = wn * 64 + ni * 32 + l31;
        #pragma unroll
        for (int j = 0; j < 2; ++j)
            boff[ni][j] = rb * BK + (((kh * 2 + j) ^ ((rb >> 1) & 3)) * 16);
    }

    auto stageA = [&](int p, int kt) {
        unsigned char* const d = smem + p * TILE_BYTES;
        #pragma unroll
        for (int j = 0; j < 4; ++j) gload_lds16(Ap + kt * BK + sAg[j], d + sAl[j]);
    };
    auto stageB = [&](int p, int kt) {
        unsigned char* const d = smem + p * TILE_BYTES + ABYTES;
        #pragma unroll
        for (int j = 0; j < 2; ++j) gload_lds16(Bp + kt * BK + sBg[j], d + sBl[j]);
    };

    f32x16 acc[4][2] = {};

    // prologue: tiles 0 and 1 staged (A then B each).  Queue [T0:6, T1:6] -> vmcnt(6).
    stageA(0, 0); stageB(0, 0);
    stageA(1, 1); stageB(1, 1);
    asm volatile("s_waitcnt vmcnt(6)" ::: "memory");
    sbar();

    int cur = 0;                          // kt % 3
    #pragma unroll 1
    for (int kt = 0; kt < NT; ++kt) {
        unsigned char* const buf = smem + cur * TILE_BYTES;
        unsigned char* const Bs  = buf + ABYTES;

        i32x8 a01[2], a23[2], bq[2];
        #pragma unroll
        for (int ni = 0; ni < 2; ++ni) {
            ((int4*)&bq[ni])[0] = *(const int4*)(Bs + boff[ni][0]);
            ((int4*)&bq[ni])[1] = *(const int4*)(Bs + boff[ni][1]);
        }
        #pragma unroll
        for (int mi = 0; mi < 2; ++mi) {
            ((int4*)&a01[mi])[0] = *(const int4*)(buf + aoff[mi][0]);
            ((int4*)&a01[mi])[1] = *(const int4*)(buf + aoff[mi][1]);
            ((int4*)&a23[mi])[0] = *(const int4*)(buf + aoff[2 + mi][0]);
            ((int4*)&a23[mi])[1] = *(const int4*)(buf + aoff[2 + mi][1]);
        }

        const int nx2 = cur;              // placeholder to keep cur live
        (void)nx2;
        if (kt + 2 < NT) {
            const int p2 = (cur + 2 >= 3) ? cur - 1 : cur + 2;   // (kt+2) % 3
            stageA(p2, kt + 2);
            stageB(p2, kt + 2);
        }

        __builtin_amdgcn_s_setprio(1);
        acc[0][0] = MFMA_FP8(a01[0], bq[0], acc[0][0]);
        acc[0][1] = MFMA_FP8(a01[0], bq[1], acc[0][1]);
        acc[1][0] = MFMA_FP8(a01[1], bq[0], acc[1][0]);
        acc[1][1] = MFMA_FP8(a01[1], bq[1], acc[1][1]);
        acc[2][0] = MFMA_FP8(a23[0], bq[0], acc[2][0]);
        acc[2][1] = MFMA_FP8(a23[0], bq[1], acc[2][1]);
        acc[3][0] = MFMA_FP8(a23[1], bq[0], acc[3][0]);
        acc[3][1] = MFMA_FP8(a23[1], bq[1], acc[3][1]);
        __builtin_amdgcn_s_setprio(0);

        if (kt < NT - 2)       { asm volatile("s_waitcnt vmcnt(6)" ::: "memory"); }
        else if (kt == NT - 2) { asm volatile("s_waitcnt vmcnt(0)" ::: "memory"); }
        if (kt < NT - 1) sbar();

        cur = (cur + 1 >= 3) ? 0 : cur + 1;
    }

    // epilogue: 32x32 C/D layout col=lane&31, row=(r&3)+8*(r>>2)+4*(lane>>5)  (m74/m101-verified)
    float bv[2];
    #pragma unroll
    for (int ni = 0; ni < 2; ++ni) bv[ni] = bias[n0 + wn * 64 + ni * 32 + l31];
    #pragma unroll
    for (int mi = 0; mi < 4; ++mi) {
        const int gmb = m0 + wm * 128 + mi * 32 + 4 * kh;
        #pragma unroll
        for (int r = 0; r < 16; ++r) {
            const int grow = gmb + (r & 3) + 8 * (r >> 2);
            float p = 0.f;
            #pragma unroll
            for (int ni = 0; ni < 2; ++ni) {
                const int gn = n0 + wn * 64 + ni * 32 + l31;
                const float val = acc[mi][ni][r] * (1.0f / 256.0f) + bv[ni];
                C[(size_t)grow * H_SZ + gn] = __float2bfloat16(val);
                p += val * val;
            }
            // cross-lane: sum over the 32 col-lanes (masks<32 stay in-half)
            p += __shfl_xor(p, 1, 64);
            p += __shfl_xor(p, 2, 64);
            p += __shfl_xor(p, 4, 64);
            p += __shfl_xor(p, 8, 64);
            p += __shfl_xor(p, 16, 64);
            if (l31 == 0) atomicAdd(ss + grow, p);
        }
    }
}

// ---------------- LIF scan: 4 columns/thread, inv-norm in LDS, 3-deep load pipeline ----------------
__global__ __launch_bounds__(256) void lif_scan_kernel(const __hip_bfloat16* __restrict__ cur, // [M_SZ,H_SZ]
                                                       const float* __restrict__ ss,           // [M_SZ] sum-of-squares
                                                       float* __restrict__ spk,                // [T,B,H]
                                                       float* __restrict__ cnt)                // [B,H]
{
    __shared__ float s_inv[T_SZ];
    const int gid = blockIdx.x * 256 + threadIdx.x;     // 262144 threads
    const int b   = gid >> 9;                           // uniform within a block
    const int h0  = (gid & 511) * 4;

    if (threadIdx.x < T_SZ)
        s_inv[threadIdx.x] = 1.0f / fmaxf(sqrtf(ss[threadIdx.x * B_SZ + b]), 1e-12f);
    __syncthreads();

    const size_t stride = (size_t)B_SZ * H_SZ;
    const size_t base   = (size_t)b * H_SZ + h0;
    const __hip_bfloat16* p = cur + base;

    ushort4 pk[3];
    pk[0] = *(const ushort4*)(p);
    pk[1] = *(const ushort4*)(p + stride);
    pk[2] = *(const ushort4*)(p + 2 * stride);

    float v[4]  = {0, 0, 0, 0};
    float cn[4] = {0, 0, 0, 0};
    #pragma unroll
    for (int t = 0; t < T_SZ; ++t) {
        const ushort4 k = pk[t % 3];
        if (t + 3 < T_SZ) pk[t % 3] = *(const ushort4*)(p + (size_t)(t + 3) * stride);
        const float inv = s_inv[t];
        float so[4];
        {
            float c;
            c = bf16_bits_to_f32(k.x) * inv; v[0] += (c - v[0]) * 0.5f;
            c = bf16_bits_to_f32(k.y) * inv; v[1] += (c - v[1]) * 0.5f;
            c = bf16_bits_to_f32(k.z) * inv; v[2] += (c - v[2]) * 0.5f;
            c = bf16_bits_to_f32(k.w) * inv; v[3] += (c - v[3]) * 0.5f;
        }
        #pragma unroll
        for (int j = 0; j < 4; ++j) {
            float s = (v[j] >= 1.0f) ? 1.0f : 0.0f;
            so[j] = s;
            cn[j] += s;
            v[j] = (s != 0.f) ? 0.f : v[j];
        }
        *(float4*)(spk + base + (size_t)t * stride) = make_float4(so[0], so[1], so[2], so[3]);
    }
    *(float4*)(cnt + base) = make_float4(cn[0], cn[1], cn[2], cn[3]);
}

extern "C" void kernel_launch(void* const* d_in, const int* in_sizes, int n_in,
                              void* d_out, int out_size, void* d_ws, size_t ws_size,
                              hipStream_t stream) {
    const float* x    = (const float*)d_in[0];   // [T,B,F] fp32
    const float* W    = (const float*)d_in[1];   // [H,F]  fp32
    const float* bias = (const float*)d_in[2];   // [H]    fp32

    float* spk = (float*)d_out;                          // [T,B,H]
    float* cnt = spk + (size_t)T_SZ * B_SZ * H_SZ;       // [B,H]

    char* ws = (char*)d_ws;
    unsigned char* x8    = (unsigned char*)ws;                                   // 33.5 MB
    unsigned char* W8    = x8 + (size_t)M_SZ * F_SZ;                             // 4.2 MB
    __hip_bfloat16* curb = (__hip_bfloat16*)(W8 + (size_t)H_SZ * F_SZ);          // 67.1 MB
    float* ss            = (float*)((char*)curb + (size_t)M_SZ * H_SZ * 2);      // 64 KB

    init_ss_kernel<<<M_SZ / 1024, 256, 0, stream>>>((float4*)ss);
    cvt_fp8_kernel<<<(M_SZ * F_SZ / 8) / 256, 256, 0, stream>>>(x, (unsigned int*)x8, 1.0f,   M_SZ * F_SZ / 8);
    cvt_fp8_kernel<<<(H_SZ * F_SZ / 8) / 256, 256, 0, stream>>>(W, (unsigned int*)W8, 256.0f, H_SZ * F_SZ / 8);
    gemm_fp8_kernel<<<dim3(H_SZ / BN, M_SZ / BM), 256, 0, stream>>>(x8, W8, bias, curb, ss);
    lif_scan_kernel<<<(B_SZ * H_SZ / 4) / 256, 256, 0, stream>>>(curb, ss, spk, cnt);
}